// Round 14
// baseline (74.035 us; speedup 1.0000x reference)
//
#include <hip/hip_runtime.h>
#include <hip/hip_bf16.h>

// Problem constants
#define B_    16
#define T_    2048
#define H_    512
#define BT_   32768      // B*T tokens
#define DIN   80         // obs 64 + act 16
#define L_    64
#define C_    32
#define O_    64
#define NCHUNK (BT_ / L_)  // 512 chunks

typedef __attribute__((ext_vector_type(8))) short short8;
typedef __attribute__((ext_vector_type(4))) float f32x4;
typedef __attribute__((ext_vector_type(4))) float float4v;

__device__ __forceinline__ float bf2f(unsigned short u) {
  union { unsigned int i; float f; } x; x.i = ((unsigned int)u) << 16; return x.f;
}
__device__ __forceinline__ unsigned short f2bf(float f) {
  union { float f; unsigned int i; } x; x.f = f;
  unsigned int r = x.i + 0x7fffu + ((x.i >> 16) & 1u);
  return (unsigned short)(r >> 16);
}

#define WB_N  (H_ * H_)
#define WO_N  (O_ * H_)

// ---------------------------------------------------------------------------
// Kernel 1: embed GEMM with inline prep (R9-proven, unchanged).
// ---------------------------------------------------------------------------
__global__ __launch_bounds__(512) void embed_gemm(
    const float* __restrict__ obs, const float* __restrict__ act,
    const float* __restrict__ W_e, const float* __restrict__ b_e,
    const float* __restrict__ a_raw, const float* __restrict__ W_B,
    const float* __restrict__ W_out,
    unsigned short* __restrict__ WBb, unsigned short* __restrict__ Woutb,
    float* __restrict__ aarr, float* __restrict__ powa,
    unsigned short* __restrict__ u)
{
  __shared__ __align__(16) unsigned char lds[131072];

  const int tid  = threadIdx.x;
  const int lane = tid & 63;
  const int wid  = tid >> 6;
  const int wr   = wid >> 2;
  const int wc   = wid & 3;
  const int cl   = lane & 15;
  const int kgrp = lane >> 4;
  const int rg   = kgrp * 4;

  const int X  = (int)blockIdx.x & 7;
  const int j  = (int)blockIdx.x >> 3;
  const int mt = X * 16 + (j >> 1);
  const int nt = j & 1;
  const int row0 = mt * 256, col0 = nt * 256;

  // Prologue: strided prep
  {
    const int g = (int)blockIdx.x * 512 + tid;
    #pragma unroll
    for (int r = 0; r < 2; ++r) {
      const int idx = g * 2 + r;
      WBb[idx] = f2bf(W_B[idx]);
    }
    if (g < WO_N) Woutb[g] = f2bf(W_out[g]);
    if (g < H_) {
      const float a = tanhf(a_raw[g]);
      aarr[g] = a;
      float p = a;
      #pragma unroll
      for (int i = 0; i < 16; ++i) { powa[i * H_ + g] = p; p *= a; }
    }
  }

  // A-tiles: inline f32->bf16, swizzled ds_write
  {
    const int row  = tid >> 1;
    const int half = tid & 1;
    {
      const float4v* src = (const float4v*)(obs + (size_t)(row0 + row) * 64 + half * 32);
      float f[32];
      #pragma unroll
      for (int i = 0; i < 8; ++i) {
        const float4v t4 = src[i];
        f[i*4+0]=t4[0]; f[i*4+1]=t4[1]; f[i*4+2]=t4[2]; f[i*4+3]=t4[3];
      }
      #pragma unroll
      for (int cc = 0; cc < 4; ++cc) {
        short8 o8;
        #pragma unroll
        for (int jj = 0; jj < 8; ++jj) o8[jj] = (short)f2bf(f[cc*8+jj]);
        const int c16 = half * 4 + cc;
        *(short8*)(lds + row * 128 + ((c16 ^ (row & 7)) << 4)) = o8;
      }
    }
    {
      short8 z8;
      #pragma unroll
      for (int jj = 0; jj < 8; ++jj) z8[jj] = 0;
      if (half == 0) {
        const float4v* asrc = (const float4v*)(act + (size_t)(row0 + row) * 16);
        float g2[16];
        #pragma unroll
        for (int i = 0; i < 4; ++i) {
          const float4v t4 = asrc[i];
          g2[i*4+0]=t4[0]; g2[i*4+1]=t4[1]; g2[i*4+2]=t4[2]; g2[i*4+3]=t4[3];
        }
        #pragma unroll
        for (int cc = 0; cc < 2; ++cc) {
          short8 o8;
          #pragma unroll
          for (int jj = 0; jj < 8; ++jj) o8[jj] = (short)f2bf(g2[cc*8+jj]);
          *(short8*)(lds + 65536 + row * 128 + ((cc ^ (row & 7)) << 4)) = o8;
        }
        #pragma unroll
        for (int cc = 2; cc < 4; ++cc)
          *(short8*)(lds + 65536 + row * 128 + ((cc ^ (row & 7)) << 4)) = z8;
      } else {
        #pragma unroll
        for (int cc = 4; cc < 8; ++cc)
          *(short8*)(lds + 65536 + row * 128 + ((cc ^ (row & 7)) << 4)) = z8;
      }
    }
  }
  // B-tiles: W_e inline f32->bf16
  {
    const int colL = tid >> 1;
    const int col  = col0 + colL;
    const int half = tid & 1;
    {
      const float4v* src = (const float4v*)(W_e + (size_t)col * DIN + half * 32);
      float f[32];
      #pragma unroll
      for (int i = 0; i < 8; ++i) {
        const float4v t4 = src[i];
        f[i*4+0]=t4[0]; f[i*4+1]=t4[1]; f[i*4+2]=t4[2]; f[i*4+3]=t4[3];
      }
      #pragma unroll
      for (int cc = 0; cc < 4; ++cc) {
        short8 o8;
        #pragma unroll
        for (int jj = 0; jj < 8; ++jj) o8[jj] = (short)f2bf(f[cc*8+jj]);
        const int c16 = half * 4 + cc;
        *(short8*)(lds + 32768 + colL * 128 + ((c16 ^ (colL & 7)) << 4)) = o8;
      }
    }
    {
      short8 z8;
      #pragma unroll
      for (int jj = 0; jj < 8; ++jj) z8[jj] = 0;
      if (half == 0) {
        const float4v* src = (const float4v*)(W_e + (size_t)col * DIN + 64);
        float g2[16];
        #pragma unroll
        for (int i = 0; i < 4; ++i) {
          const float4v t4 = src[i];
          g2[i*4+0]=t4[0]; g2[i*4+1]=t4[1]; g2[i*4+2]=t4[2]; g2[i*4+3]=t4[3];
        }
        #pragma unroll
        for (int cc = 0; cc < 2; ++cc) {
          short8 o8;
          #pragma unroll
          for (int jj = 0; jj < 8; ++jj) o8[jj] = (short)f2bf(g2[cc*8+jj]);
          *(short8*)(lds + 98304 + colL * 128 + ((cc ^ (colL & 7)) << 4)) = o8;
        }
        #pragma unroll
        for (int cc = 2; cc < 4; ++cc)
          *(short8*)(lds + 98304 + colL * 128 + ((cc ^ (colL & 7)) << 4)) = z8;
      } else {
        #pragma unroll
        for (int cc = 4; cc < 8; ++cc)
          *(short8*)(lds + 98304 + colL * 128 + ((cc ^ (colL & 7)) << 4)) = z8;
      }
    }
  }
  __syncthreads();

  f32x4 acc[8][4];
  #pragma unroll
  for (int m = 0; m < 8; ++m)
    #pragma unroll
    for (int n = 0; n < 4; ++n) acc[m][n] = f32x4{0.f, 0.f, 0.f, 0.f};

  #pragma unroll
  for (int q = 0; q < 2; ++q) {
    const unsigned char* bufp = lds + q * 65536;
    short8 bfr[4][2];
    #pragma unroll
    for (int n = 0; n < 4; ++n) {
      const int col = wc * 64 + n * 16 + cl;
      #pragma unroll
      for (int ks = 0; ks < 2; ++ks)
        bfr[n][ks] = *(const short8*)(bufp + 32768 + col * 128 +
                                      ((((ks << 2) + kgrp) ^ (col & 7)) << 4));
    }
    #pragma unroll
    for (int g = 0; g < 4; ++g) {
      short8 af[2][2];
      #pragma unroll
      for (int mm = 0; mm < 2; ++mm) {
        const int row = wr * 128 + (g * 2 + mm) * 16 + cl;
        #pragma unroll
        for (int ks = 0; ks < 2; ++ks)
          af[mm][ks] = *(const short8*)(bufp + row * 128 +
                                        ((((ks << 2) + kgrp) ^ (row & 7)) << 4));
      }
      #pragma unroll
      for (int ks = 0; ks < 2; ++ks)
        #pragma unroll
        for (int mm = 0; mm < 2; ++mm)
          #pragma unroll
          for (int n = 0; n < 4; ++n)
            acc[g * 2 + mm][n] = __builtin_amdgcn_mfma_f32_16x16x32_bf16(
                af[mm][ks], bfr[n][ks], acc[g * 2 + mm][n], 0, 0, 0);
    }
  }

  #pragma unroll
  for (int m = 0; m < 8; ++m) {
    #pragma unroll
    for (int n = 0; n < 4; ++n) {
      const int gc = col0 + wc * 64 + n * 16 + cl;
      const float be = b_e[gc];
      #pragma unroll
      for (int e2 = 0; e2 < 4; ++e2) {
        const int gr = row0 + wr * 128 + m * 16 + rg + e2;
        u[(size_t)gr * H_ + gc] = f2bf(fmaxf(acc[m][n][e2] + be, 0.f));
      }
    }
  }
}

// ---------------------------------------------------------------------------
// Kernel 2: B-projection GEMM — occupancy A/B vs R9: BM=128, BN=128, BK=64
// (UNCHANGED BK and schedule vs R9; only tile/block size shrunk).
// 256 threads = 4 waves (2M x 2N), wave C = 64x64 (4m x 4n frags, 64 acc
// VGPR). LDS = 2 buf x (A 16KB + B 16KB) = 64KB -> 2 independent blocks/CU
// (launch_bounds(256,2)): one block's barrier drain no longer stalls the
// other block's waves. Grid 1024: X=bid&7, mt=X*32+(j>>2), nt=j&3 -> the 4
// nt-blocks of an mt share the u-slab within one XCD's L2, and e-chunks
// [64X, 64X+64) stay on XCD X (same map scan_out expects).
// Counted-vmcnt schedule identical to R9 (3 barriers per K-tile, NT=8).
// CE epilogue: wave wr owns exactly chunk mt*2+wr (FM=4 verified Horner).
// ---------------------------------------------------------------------------
__global__ __launch_bounds__(256, 2) void gemm_bproj(
    const unsigned short* __restrict__ A, const unsigned short* __restrict__ Bt,
    unsigned short* __restrict__ Cb,
    const float* __restrict__ powa, float* __restrict__ e)
{
  constexpr int NT = 8;                 // K = 512 / 64
  constexpr int ABYTES = 128 * 64 * 2;  // 16384
  constexpr int TOT = 2 * ABYTES;       // 32768 per buffer
  __shared__ __align__(16) unsigned char lds[2 * TOT];   // 64 KB

  const int tid  = threadIdx.x;
  const int lane = tid & 63;
  const int wid  = tid >> 6;
  const int wr   = wid >> 1;            // 0..1 (M)
  const int wc   = wid & 1;             // 0..1 (N)
  const int cl   = lane & 15;
  const int kgrp = lane >> 4;
  const int rg   = kgrp * 4;

  const int X  = (int)blockIdx.x & 7;
  const int j  = (int)blockIdx.x >> 3;     // 0..127
  const int mt = X * 32 + (j >> 2);        // 0..255
  const int nt = j & 3;                    // 0..3
  const int row0 = mt * 128, col0 = nt * 128;

  auto stageA = [&](int q, int buf) {      // 4 rounds x 4KB
    const int k0 = q * 64;
    #pragma unroll
    for (int r = 0; r < 4; ++r) {
      const int o   = r * 4096 + tid * 16;
      const int row = o >> 7;
      const int c16 = (o >> 4) & 7;
      const int kk  = (c16 ^ (row & 7)) << 3;
      __builtin_amdgcn_global_load_lds(
          (const __attribute__((address_space(1))) void*)
              (A + (size_t)(row0 + row) * H_ + k0 + kk),
          (__attribute__((address_space(3))) void*)(lds + buf * TOT + o),
          16, 0, 0);
    }
  };
  auto stageB_round = [&](int q, int buf, int r) {   // 4KB each
    const int k0 = q * 64;
    const int o   = r * 4096 + tid * 16;
    const int col = o >> 7;
    const int c16 = (o >> 4) & 7;
    const int kk  = (c16 ^ (col & 7)) << 3;
    __builtin_amdgcn_global_load_lds(
        (const __attribute__((address_space(1))) void*)
            (Bt + (size_t)(col0 + col) * H_ + k0 + kk),
        (__attribute__((address_space(3))) void*)(lds + buf * TOT + ABYTES + o),
        16, 0, 0);
  };

  f32x4 acc[4][4];
  #pragma unroll
  for (int m = 0; m < 4; ++m)
    #pragma unroll
    for (int n = 0; n < 4; ++n) acc[m][n] = f32x4{0.f, 0.f, 0.f, 0.f};

  // Prologue: A0,B0 -> buf0; B1 -> buf1; wait A0+B0 (8 oldest of 12).
  stageA(0, 0);
  #pragma unroll
  for (int r = 0; r < 4; ++r) stageB_round(0, 0, r);
  #pragma unroll
  for (int r = 0; r < 4; ++r) stageB_round(1, 1, r);
  asm volatile("s_waitcnt vmcnt(4)" ::: "memory");
  __builtin_amdgcn_sched_barrier(0);
  __builtin_amdgcn_s_barrier();

  for (int q = 0; q < NT; ++q) {
    const int cur = q & 1;
    const unsigned char* bufp = lds + cur * TOT;

    if (q + 1 < NT) stageA(q + 1, cur ^ 1);

    // bfr preload: 4 n-frags x 2 ks = 8 ds_read_b128 from buf[cur].B
    short8 bfr[4][2];
    #pragma unroll
    for (int n = 0; n < 4; ++n) {
      const int col = wc * 64 + n * 16 + cl;
      #pragma unroll
      for (int ks = 0; ks < 2; ++ks)
        bfr[n][ks] = *(const short8*)(bufp + ABYTES + col * 128 +
                                      ((((ks << 2) + kgrp) ^ (col & 7)) << 4));
    }
    asm volatile("s_waitcnt lgkmcnt(0)" ::: "memory");
    __builtin_amdgcn_sched_barrier(0);
    __builtin_amdgcn_s_barrier();            // bar1: all B reads of cur done

    __builtin_amdgcn_s_setprio(1);
    #pragma unroll
    for (int g = 0; g < 4; ++g) {
      if (q + 2 < NT) stageB_round(q + 2, cur, g);   // reads of cur.B done
      short8 af[2];
      const int row = wr * 64 + g * 16 + cl;
      #pragma unroll
      for (int ks = 0; ks < 2; ++ks)
        af[ks] = *(const short8*)(bufp + row * 128 +
                                  ((((ks << 2) + kgrp) ^ (row & 7)) << 4));
      #pragma unroll
      for (int ks = 0; ks < 2; ++ks)
        #pragma unroll
        for (int n = 0; n < 4; ++n)
          acc[g][n] = __builtin_amdgcn_mfma_f32_16x16x32_bf16(
              af[ks], bfr[n][ks], acc[g][n], 0, 0, 0);
    }
    __builtin_amdgcn_s_setprio(0);

    if (q + 2 < NT) {
      asm volatile("s_waitcnt vmcnt(4)" ::: "memory");  // A(q+1),B(q+1) done
    } else if (q + 1 < NT) {
      asm volatile("s_waitcnt vmcnt(0)" ::: "memory");
    }
    __builtin_amdgcn_sched_barrier(0);
    __builtin_amdgcn_s_barrier();            // bar2
  }

  // Epilogue: v write. D[r][c]: c = lane&15, r = (lane>>4)*4 + e2
  #pragma unroll
  for (int m = 0; m < 4; ++m) {
    #pragma unroll
    for (int n = 0; n < 4; ++n) {
      const int gc = col0 + wc * 64 + n * 16 + cl;
      #pragma unroll
      for (int e2 = 0; e2 < 4; ++e2) {
        const int gr = row0 + wr * 64 + m * 16 + rg + e2;
        Cb[(size_t)gr * H_ + gc] = f2bf(acc[m][n][e2]);
      }
    }
  }

  // Chunk-end e: wave wr owns chunk mt*2+wr (rows wr*64..+63).
  // i = m*16 + rg + e2; a^{63-i} = a^{15-rg-e2} * (a^16)^{3-m}.
  {
    const int chunk = mt * 2 + wr;
    #pragma unroll
    for (int n = 0; n < 4; ++n) {
      const int h = col0 + wc * 64 + n * 16 + cl;
      const float a16 = powa[15 * H_ + h];
      float ep = 0.f;
      #pragma unroll
      for (int e2 = 0; e2 < 4; ++e2) {
        const int k = 15 - rg - e2;
        const float wk = (k == 0) ? 1.f : powa[(size_t)(k - 1) * H_ + h];
        float hsum = acc[0][n][e2];
        hsum = fmaf(hsum, a16, acc[1][n][e2]);
        hsum = fmaf(hsum, a16, acc[2][n][e2]);
        hsum = fmaf(hsum, a16, acc[3][n][e2]);
        ep = fmaf(wk, hsum, ep);
      }
      ep += __shfl_xor(ep, 16);
      ep += __shfl_xor(ep, 32);
      if (kgrp == 0)
        e[(size_t)chunk * H_ + h] = ep;
    }
  }
}

// ---------------------------------------------------------------------------
// Kernel 3: fused carry + scan + out-projection (R12-proven, unchanged;
// chunk map matches producer XCDs: chunk = (bid&7)*64 + bid>>3).
// ---------------------------------------------------------------------------
__global__ __launch_bounds__(256) void scan_out(
    const unsigned int* __restrict__ v, const float* __restrict__ e,
    const float* __restrict__ aarr, const unsigned short* __restrict__ Wo,
    const float* __restrict__ b_out, float* __restrict__ y)
{
  __shared__ __align__(16) unsigned char sbytes[64 * 1024];
  const int blk = ((int)blockIdx.x & 7) * 64 + ((int)blockIdx.x >> 3);
  const int b = blk >> 5, c = blk & 31;
  const int tid = threadIdx.x;
  const int lane = tid & 63, w = tid >> 6;
  const int row_base = blk * L_;

  {
    const int h0 = tid * 2;
    const float a0 = aarr[h0], a1 = aarr[h0 + 1];
    float aL0 = a0 * a0, aL1 = a1 * a1;
    aL0 *= aL0; aL1 *= aL1;
    aL0 *= aL0; aL1 *= aL1;
    aL0 *= aL0; aL1 *= aL1;
    aL0 *= aL0; aL1 *= aL1;
    aL0 *= aL0; aL1 *= aL1;                       // a^64
    float s0 = 0.f, s1 = 0.f;
    #pragma unroll
    for (int g = 0; g < 4; ++g) {
      float ev0[8], ev1[8];
      #pragma unroll
      for (int k = 0; k < 8; ++k) {
        const size_t o = ((size_t)(b * C_ + g * 8 + k)) * H_ + h0;
        ev0[k] = e[o]; ev1[k] = e[o + 1];
      }
      #pragma unroll
      for (int k = 0; k < 8; ++k) {
        const bool pred = (g * 8 + k) < c;
        s0 = pred ? fmaf(aL0, s0, ev0[k]) : s0;
        s1 = pred ? fmaf(aL1, s1, ev1[k]) : s1;
      }
    }
    const unsigned int* vp = v + (size_t)row_base * (H_ / 2) + tid;
    #pragma unroll 8
    for (int t = 0; t < L_; ++t) {
      const unsigned int pv = vp[(size_t)t * (H_ / 2)];
      s0 = fmaf(a0, s0, bf2f((unsigned short)(pv & 0xffff)));
      s1 = fmaf(a1, s1, bf2f((unsigned short)(pv >> 16)));
      const int byte = t * 1024 + ((tid * 4) ^ ((t & 7) << 4));
      *(unsigned int*)(sbytes + byte) =
          (unsigned int)f2bf(s0) | ((unsigned int)f2bf(s1) << 16);
    }
  }
  __syncthreads();

  f32x4 acc[4];
  #pragma unroll
  for (int n = 0; n < 4; ++n) acc[n] = f32x4{0.f, 0.f, 0.f, 0.f};
  const int r = w * 16 + (lane & 15);
  const int kof = (lane >> 4) * 8;
  #pragma unroll 4
  for (int k0 = 0; k0 < H_; k0 += 32) {
    const int byte = r * 1024 + (((k0 + kof) * 2) ^ ((r & 7) << 4));
    const short8 af = *(const short8*)(sbytes + byte);
    #pragma unroll
    for (int n = 0; n < 4; ++n) {
      const short8 bf = *(const short8*)(Wo + (size_t)(n * 16 + (lane & 15)) * H_ + k0 + kof);
      acc[n] = __builtin_amdgcn_mfma_f32_16x16x32_bf16(af, bf, acc[n], 0, 0, 0);
    }
  }
  const int cl = lane & 15, rg = (lane >> 4) * 4;
  #pragma unroll
  for (int n = 0; n < 4; ++n) {
    #pragma unroll
    for (int e2 = 0; e2 < 4; ++e2) {
      const int gr = row_base + w * 16 + rg + e2;
      const int gc = n * 16 + cl;
      y[(size_t)gr * O_ + gc] = acc[n][e2] + b_out[gc];
    }
  }
}

// ---------------------------------------------------------------------------
extern "C" void kernel_launch(void* const* d_in, const int* in_sizes, int n_in,
                              void* d_out, int out_size, void* d_ws, size_t ws_size,
                              hipStream_t stream)
{
  const float* obs   = (const float*)d_in[0];
  const float* act   = (const float*)d_in[1];
  const float* W_e   = (const float*)d_in[2];
  const float* b_e   = (const float*)d_in[3];
  const float* a_raw = (const float*)d_in[4];
  const float* W_B   = (const float*)d_in[5];
  const float* W_out = (const float*)d_in[6];
  const float* b_out = (const float*)d_in[7];
  float* y = (float*)d_out;

  char* w = (char*)d_ws;
  auto carve = [&](size_t bytes) {
    char* p = w; w += (bytes + 255) & ~(size_t)255; return p;
  };
  unsigned short* WBb   = (unsigned short*)carve((size_t)H_ * H_ * 2);
  unsigned short* Woutb = (unsigned short*)carve((size_t)O_ * H_ * 2);
  float*          aarr  = (float*)carve((size_t)H_ * 4);
  float*          powa  = (float*)carve((size_t)16 * H_ * 4);
  unsigned short* u     = (unsigned short*)carve((size_t)BT_ * H_ * 2);   // 33.5 MB
  unsigned short* v     = (unsigned short*)carve((size_t)BT_ * H_ * 2);   // 33.5 MB
  float*          e     = (float*)carve((size_t)NCHUNK * H_ * 4);         // 1 MB

  // 1) embed (+ inline weight prep) -> u
  embed_gemm<<<256, 512, 0, stream>>>(obs, act, W_e, b_e, a_raw, W_B, W_out,
                                      WBb, Woutb, aarr, powa, u);
  // 2) v = u @ WB^T (128x128 tile, BK=64, 2 blocks/CU); epilogue emits e
  gemm_bproj<<<1024, 256, 0, stream>>>(u, WBb, v, powa, e);
  // 3) fused carry + scan + out-projection -> y
  scan_out<<<NCHUNK, 256, 0, stream>>>((const unsigned int*)v, e, aarr,
                                       Woutb, b_out, y);
}